// Round 11
// baseline (178.577 us; speedup 1.0000x reference)
//
#include <hip/hip_runtime.h>

#pragma clang fp contract(off)

#define IMG_H 512
#define IMG_W 512

__device__ __forceinline__ int reflect_idx(int i) {
    // jnp.pad 'reflect': -1 -> 1, 512 -> 510
    i = (i < 0) ? -i : i;
    i = (i >= IMG_H) ? (2 * IMG_H - 2 - i) : i;
    return i;
}

__device__ __forceinline__ float gray1(float a0, float a1, float a2) {
    // bit-identical T_a gray conversion (verified absmax=0.0)
    return (0.144f * a0 + 0.587f * a1) + 0.299f * a2;
}

__device__ __forceinline__ float4 gray4(float4 c0, float4 c1, float4 c2) {
    float4 g;
    g.x = (0.144f * c0.x + 0.587f * c1.x) + 0.299f * c2.x;
    g.y = (0.144f * c0.y + 0.587f * c1.y) + 0.299f * c2.y;
    g.z = (0.144f * c0.z + 0.587f * c1.z) + 0.299f * c2.z;
    g.w = (0.144f * c0.w + 0.587f * c1.w) + 0.299f * c2.w;
    return g;
}

// One window-row fold, dx ascending (bit-identical T_a chain order).
#define ACC5(S, Q, e0, e1, e2, e3, e4)                                       \
    S = S + (e0); Q = Q + (e0) * (e0);                                       \
    S = S + (e1); Q = Q + (e1) * (e1);                                       \
    S = S + (e2); Q = Q + (e2) * (e2);                                       \
    S = S + (e3); Q = Q + (e3) * (e3);                                       \
    S = S + (e4); Q = Q + (e4) * (e4);

// Register-only, barrier-free, LDS-free kernel.
// Lane = (cq 0..15, rq 0..3): output cols x0+4cq..x0+4cq+3, rows yb,yb+1
// (yb = blockIdx.y*32 + wave*8 + 2*rq). Streams 6 global rows (yb-2..yb+3)
// ascending; each row: own gray quad from aligned float4 channel loads,
// +-2 col halo from __shfl of neighbor lanes (16-lane row groups), tile
// edges from lane-masked float2/scalar loads with reflect. Each of the 8
// output chains receives its 25 values in row-major/dx-ascending order
// from acc=0.0f with recip-mul mean -> bit-identical to verified T_a.
// No __syncthreads anywhere: 4 independent waves/block, phases decorrelate
// at instruction granularity (one wave's loads under another's folds).
__global__ __launch_bounds__(256) void texdiff_kernel(
        const float* __restrict__ img1,
        const float* __restrict__ img2,
        float* __restrict__ out) {
    const int tid  = threadIdx.x;
    const int wv   = tid >> 6;
    const int lane = tid & 63;
    const int cq   = lane & 15;
    const int rq   = lane >> 4;

    const int b  = blockIdx.z;
    const int x0 = blockIdx.x * 64;
    const int yb = blockIdx.y * 32 + wv * 8 + rq * 2;   // first output row

    const size_t plane = (size_t)IMG_H * IMG_W;
    const float* i1 = img1 + (size_t)b * 3 * plane;
    const float* i2 = img2 + (size_t)b * 3 * plane;

    const int gxq = x0 + 4 * cq;
    const bool isL = (cq == 0);
    const bool isR = (cq == 15);

    float s1[2][4], q1[2][4], s2[2][4], q2[2][4];
    #pragma unroll
    for (int wi = 0; wi < 2; ++wi) {
        #pragma unroll
        for (int j = 0; j < 4; ++j) {
            s1[wi][j] = 0.0f; q1[wi][j] = 0.0f;
            s2[wi][j] = 0.0f; q2[wi][j] = 0.0f;
        }
    }

    #pragma unroll
    for (int sr = 0; sr < 6; ++sr) {
        const int gy = reflect_idx(yb - 2 + sr);
        const float* pa = i1 + (size_t)gy * IMG_W + gxq;
        const float* pb = i2 + (size_t)gy * IMG_W + gxq;
        float4 A0 = *(const float4*)(pa);
        float4 A1 = *(const float4*)(pa + plane);
        float4 A2 = *(const float4*)(pa + 2 * plane);
        float4 B0 = *(const float4*)(pb);
        float4 B1 = *(const float4*)(pb + plane);
        float4 B2 = *(const float4*)(pb + 2 * plane);

        // ---- tile-edge halo grays (lane-masked; block-uniform inner) ----
        float gl2a = 0.f, gl1a = 0.f, gl2b = 0.f, gl1b = 0.f;
        float gr1a = 0.f, gr2a = 0.f, gr1b = 0.f, gr2b = 0.f;
        if (isL) {
            const float* ha = i1 + (size_t)gy * IMG_W;
            const float* hb = i2 + (size_t)gy * IMG_W;
            if (x0 != 0) {   // cols x0-2, x0-1 (8B-aligned float2)
                const float* la = ha + (x0 - 2);
                const float* lb = hb + (x0 - 2);
                float2 H0 = *(const float2*)(la);
                float2 H1 = *(const float2*)(la + plane);
                float2 H2 = *(const float2*)(la + 2 * plane);
                float2 G0 = *(const float2*)(lb);
                float2 G1 = *(const float2*)(lb + plane);
                float2 G2 = *(const float2*)(lb + 2 * plane);
                gl2a = gray1(H0.x, H1.x, H2.x);
                gl1a = gray1(H0.y, H1.y, H2.y);
                gl2b = gray1(G0.x, G1.x, G2.x);
                gl1b = gray1(G0.y, G1.y, G2.y);
            } else {         // cols -2,-1 -> reflect 2,1 (scalar loads)
                gl2a = gray1(ha[2], ha[plane + 2], ha[2 * plane + 2]);
                gl1a = gray1(ha[1], ha[plane + 1], ha[2 * plane + 1]);
                gl2b = gray1(hb[2], hb[plane + 2], hb[2 * plane + 2]);
                gl1b = gray1(hb[1], hb[plane + 1], hb[2 * plane + 1]);
            }
        }
        if (isR) {
            const float* ha = i1 + (size_t)gy * IMG_W;
            const float* hb = i2 + (size_t)gy * IMG_W;
            if (x0 != 448) { // cols x0+64, x0+65 (aligned float2)
                const float* ra = ha + (x0 + 64);
                const float* rb = hb + (x0 + 64);
                float2 H0 = *(const float2*)(ra);
                float2 H1 = *(const float2*)(ra + plane);
                float2 H2 = *(const float2*)(ra + 2 * plane);
                float2 G0 = *(const float2*)(rb);
                float2 G1 = *(const float2*)(rb + plane);
                float2 G2 = *(const float2*)(rb + 2 * plane);
                gr1a = gray1(H0.x, H1.x, H2.x);
                gr2a = gray1(H0.y, H1.y, H2.y);
                gr1b = gray1(G0.x, G1.x, G2.x);
                gr2b = gray1(G0.y, G1.y, G2.y);
            } else {         // cols 512,513 -> reflect 510,509 (scalar)
                gr1a = gray1(ha[510], ha[plane + 510], ha[2 * plane + 510]);
                gr2a = gray1(ha[509], ha[plane + 509], ha[2 * plane + 509]);
                gr1b = gray1(hb[510], hb[plane + 510], hb[2 * plane + 510]);
                gr2b = gray1(hb[509], hb[plane + 509], hb[2 * plane + 509]);
            }
        }

        float4 va = gray4(A0, A1, A2);
        float4 vb = gray4(B0, B1, B2);

        // ---- neighbor-lane halo via wave shuffles (uniform exec) ----
        const int lm = (lane - 1) & 63;
        const int lp = (lane + 1) & 63;
        float l2a = __shfl(va.z, lm), l1a = __shfl(va.w, lm);
        float r1a = __shfl(va.x, lp), r2a = __shfl(va.y, lp);
        float l2b = __shfl(vb.z, lm), l1b = __shfl(vb.w, lm);
        float r1b = __shfl(vb.x, lp), r2b = __shfl(vb.y, lp);
        if (isL) { l2a = gl2a; l1a = gl1a; l2b = gl2b; l1b = gl1b; }
        if (isR) { r1a = gr1a; r2a = gr2a; r1b = gr1b; r2b = gr2b; }

        // ---- fold this row into active windows (rows ascend, dx ascends) ----
        #pragma unroll
        for (int wi = 0; wi < 2; ++wi) {
            if (sr >= wi && sr <= wi + 4) {   // compile-time predicate
                ACC5(s1[wi][0], q1[wi][0], l2a, l1a, va.x, va.y, va.z)
                ACC5(s1[wi][1], q1[wi][1], l1a, va.x, va.y, va.z, va.w)
                ACC5(s1[wi][2], q1[wi][2], va.x, va.y, va.z, va.w, r1a)
                ACC5(s1[wi][3], q1[wi][3], va.y, va.z, va.w, r1a, r2a)
                ACC5(s2[wi][0], q2[wi][0], l2b, l1b, vb.x, vb.y, vb.z)
                ACC5(s2[wi][1], q2[wi][1], l1b, vb.x, vb.y, vb.z, vb.w)
                ACC5(s2[wi][2], q2[wi][2], vb.x, vb.y, vb.z, vb.w, r1b)
                ACC5(s2[wi][3], q2[wi][3], vb.y, vb.z, vb.w, r1b, r2b)
            }
        }
    }

    // ---- epilogue (verified formula) + 2 coalesced float4 stores ----
    #pragma unroll
    for (int wi = 0; wi < 2; ++wi) {
        float4 o;
        #pragma unroll
        for (int j = 0; j < 4; ++j) {
            float m1 = s1[wi][j] * 0.04f;
            float e1 = q1[wi][j] * 0.04f;
            float m2 = s2[wi][j] * 0.04f;
            float e2 = q2[wi][j] * 0.04f;
            float var1 = fmaxf(e1 - m1 * m1, 0.0f);
            float sd1 = sqrtf(var1 + 1e-9f);
            float var2 = fmaxf(e2 - m2 * m2, 0.0f);
            float sd2 = sqrtf(var2 + 1e-9f);
            float num = (2.0f * sd1) * sd2;
            float den = ((sd1 * sd1 + sd2 * sd2) + 1e-5f) + 1e-8f;
            float val = (num / den > 0.975f) ? 1.0f : 0.0f;
            (j == 0 ? o.x : j == 1 ? o.y : j == 2 ? o.z : o.w) = val;
        }
        *reinterpret_cast<float4*>(
            &out[((size_t)b * IMG_H + (yb + wi)) * IMG_W + gxq]) = o;
    }
}

extern "C" void kernel_launch(void* const* d_in, const int* in_sizes, int n_in,
                              void* d_out, int out_size, void* d_ws, size_t ws_size,
                              hipStream_t stream) {
    const float* img1 = (const float*)d_in[0];
    const float* img2 = (const float*)d_in[1];
    float* out = (float*)d_out;
    dim3 grid(IMG_W / 64, IMG_H / 32, 16);   // 8 x 16 x 16 = 2048 blocks
    texdiff_kernel<<<grid, dim3(256), 0, stream>>>(img1, img2, out);
}

// Round 13
// 133.826 us; speedup vs baseline: 1.3344x; 1.3344x over previous
//
#include <hip/hip_runtime.h>

#pragma clang fp contract(off)

#define IMG_H 512
#define IMG_W 512
#define TILE_W 64
#define TILE_H 32
#define PAD 2
#define LROWS 36                 // TILE_H + 2*PAD
#define LCOLS 70                 // padded float2 width (2 + 64 + 2 = 68, pad to 70)
#define NTHREADS 256

typedef float f32x2 __attribute__((ext_vector_type(2)));

__device__ __forceinline__ int reflect_idx(int i) {
    // jnp.pad 'reflect': -1 -> 1, 512 -> 510
    i = (i < 0) ? -i : i;
    i = (i >= IMG_H) ? (2 * IMG_H - 2 - i) : i;
    return i;
}

__device__ __forceinline__ float2 gray2(float a0, float a1, float a2,
                                        float b0, float b1, float b2) {
    // bit-identical T_a gray conversion (verified absmax=0.0)
    float2 g;
    g.x = (0.144f * a0 + 0.587f * a1) + 0.299f * a2;
    g.y = (0.144f * b0 + 0.587f * b1) + 0.299f * b2;
    return g;
}

// ---- staging: verbatim R5 (84 VGPR, no spill, verified absmax=0.0) ----
__device__ __forceinline__ void stage_tile(float2 (*buf)[LCOLS],
        const float* __restrict__ i1, const float* __restrict__ i2,
        int x0, int y0, int tid) {
    const size_t plane = (size_t)IMG_H * IMG_W;

    int it0 = tid;                 // rows 0..15
    int it1 = tid + NTHREADS;      // rows 16..31
    int r0 = it0 >> 4, q0 = it0 & 15;
    int r1 = it1 >> 4, q1 = it1 & 15;
    int gy0 = reflect_idx(y0 + r0 - PAD);
    int gy1 = reflect_idx(y0 + r1 - PAD);
    const float* pa0 = i1 + (size_t)gy0 * IMG_W + (x0 + 4 * q0);
    const float* pb0 = i2 + (size_t)gy0 * IMG_W + (x0 + 4 * q0);
    const float* pa1 = i1 + (size_t)gy1 * IMG_W + (x0 + 4 * q1);
    const float* pb1 = i2 + (size_t)gy1 * IMG_W + (x0 + 4 * q1);

    float4 A0 = *(const float4*)(pa0);
    float4 A1 = *(const float4*)(pa0 + plane);
    float4 A2 = *(const float4*)(pa0 + 2 * plane);
    float4 B0 = *(const float4*)(pb0);
    float4 B1 = *(const float4*)(pb0 + plane);
    float4 B2 = *(const float4*)(pb0 + 2 * plane);
    float4 C0 = *(const float4*)(pa1);
    float4 C1 = *(const float4*)(pa1 + plane);
    float4 C2 = *(const float4*)(pa1 + 2 * plane);
    float4 D0 = *(const float4*)(pb1);
    float4 D1 = *(const float4*)(pb1 + plane);
    float4 D2 = *(const float4*)(pb1 + 2 * plane);

    {
        float2 g0 = gray2(A0.x, A1.x, A2.x, B0.x, B1.x, B2.x);
        float2 g1 = gray2(A0.y, A1.y, A2.y, B0.y, B1.y, B2.y);
        float2 g2 = gray2(A0.z, A1.z, A2.z, B0.z, B1.z, B2.z);
        float2 g3 = gray2(A0.w, A1.w, A2.w, B0.w, B1.w, B2.w);
        float4* dst = (float4*)&buf[r0][2 + 4 * q0];   // 16B-aligned
        dst[0] = make_float4(g0.x, g0.y, g1.x, g1.y);
        dst[1] = make_float4(g2.x, g2.y, g3.x, g3.y);
    }
    {
        float2 g0 = gray2(C0.x, C1.x, C2.x, D0.x, D1.x, D2.x);
        float2 g1 = gray2(C0.y, C1.y, C2.y, D0.y, D1.y, D2.y);
        float2 g2 = gray2(C0.z, C1.z, C2.z, D0.z, D1.z, D2.z);
        float2 g3 = gray2(C0.w, C1.w, C2.w, D0.w, D1.w, D2.w);
        float4* dst = (float4*)&buf[r1][2 + 4 * q1];
        dst[0] = make_float4(g0.x, g0.y, g1.x, g1.y);
        dst[1] = make_float4(g2.x, g2.y, g3.x, g3.y);
    }

    if (tid < 64) {   // tail: rows 32..35
        int it2 = tid + 2 * NTHREADS;
        int r2 = it2 >> 4, q2 = it2 & 15;
        int gy2 = reflect_idx(y0 + r2 - PAD);
        const float* pa2 = i1 + (size_t)gy2 * IMG_W + (x0 + 4 * q2);
        const float* pb2 = i2 + (size_t)gy2 * IMG_W + (x0 + 4 * q2);
        float4 E0 = *(const float4*)(pa2);
        float4 E1 = *(const float4*)(pa2 + plane);
        float4 E2 = *(const float4*)(pa2 + 2 * plane);
        float4 F0 = *(const float4*)(pb2);
        float4 F1 = *(const float4*)(pb2 + plane);
        float4 F2 = *(const float4*)(pb2 + 2 * plane);
        float2 g0 = gray2(E0.x, E1.x, E2.x, F0.x, F1.x, F2.x);
        float2 g1 = gray2(E0.y, E1.y, E2.y, F0.y, F1.y, F2.y);
        float2 g2 = gray2(E0.z, E1.z, E2.z, F0.z, F1.z, F2.z);
        float2 g3 = gray2(E0.w, E1.w, E2.w, F0.w, F1.w, F2.w);
        float4* dst = (float4*)&buf[r2][2 + 4 * q2];
        dst[0] = make_float4(g0.x, g0.y, g1.x, g1.y);
        dst[1] = make_float4(g2.x, g2.y, g3.x, g3.y);
    }

    if (tid < 144) {   // halo: 36 rows x cols {0,1,66,67}
        int r = tid >> 2, s = tid & 3;
        int c = (s < 2) ? s : (s + 64);
        int gy = reflect_idx(y0 + r - PAD);
        int gx = reflect_idx(x0 + c - PAD);
        size_t off = (size_t)gy * IMG_W + gx;
        buf[r][c] = gray2(i1[off], i1[off + plane], i1[off + 2 * plane],
                          i2[off], i2[off + plane], i2[off + 2 * plane]);
    }
}

// T_a chains (verified absmax=0.0): rows ascend, dx ascends within row,
// acc starts 0.0f, mean via s*0.04f recip-mul. PACKED-F32 fold: img1/img2
// chains are independent & identical and the LDS layout interleaves
// (gray1,gray2) as float2 -> accumulate both with <2 x float> ops
// (v_pk_add_f32 / v_pk_mul_f32; per-lane IEEE f32, same rounding).
// R12 BUG FIXED: `(f32x2)(a,b)` was a comma-expression cast (broadcast of
// b); proper brace-init `{a,b}` is used here.
__global__ __launch_bounds__(NTHREADS) void texdiff_kernel(
        const float* __restrict__ img1,
        const float* __restrict__ img2,
        float* __restrict__ out) {
    __shared__ float2 g12[LROWS][LCOLS];   // 36*70*8 = 20,160 B

    const int b  = blockIdx.z;
    const int x0 = blockIdx.x * TILE_W;
    const int y0 = blockIdx.y * TILE_H;
    const int tid = threadIdx.x;

    const size_t plane = (size_t)IMG_H * IMG_W;
    const float* i1 = img1 + (size_t)b * 3 * plane;
    const float* i2 = img2 + (size_t)b * 3 * plane;

    stage_tile(g12, i1, i2, x0, y0, tid);
    __syncthreads();

    const int cx = tid & 31;       // col-pair: cols 2cx, 2cx+1
    const int ry = tid >> 5;       // 0..7 -> rows ry*4 .. ry*4+3
    const int r0 = ry * 4;
    const int cb = 2 * cx;

    // s[k][j] = (sum_img1, sum_img2); q[k][j] = (sumsq_img1, sumsq_img2)
    f32x2 s[4][2], q[4][2];
    #pragma unroll
    for (int k = 0; k < 4; ++k) {
        #pragma unroll
        for (int j = 0; j < 2; ++j) {
            f32x2 z = {0.0f, 0.0f};
            s[k][j] = z;
            q[k][j] = z;
        }
    }

    // 8 LDS rows serve 4 overlapping windows; each row read ONCE (3x b128).
    #pragma unroll
    for (int rr = 0; rr < 8; ++rr) {
        const float4* vp = (const float4*)&g12[r0 + rr][cb];  // 16B-aligned
        float4 w0 = vp[0], w1 = vp[1], w2 = vp[2];
        f32x2 v[6];
        v[0] = f32x2{w0.x, w0.y}; v[1] = f32x2{w0.z, w0.w};
        v[2] = f32x2{w1.x, w1.y}; v[3] = f32x2{w1.z, w1.w};
        v[4] = f32x2{w2.x, w2.y}; v[5] = f32x2{w2.z, w2.w};

        #pragma unroll
        for (int k = 0; k < 4; ++k) {
            if (rr >= k && rr <= k + 4) {   // compile-time predicate
                #pragma unroll
                for (int j = 0; j < 2; ++j) {
                    #pragma unroll
                    for (int dx = 0; dx < 5; ++dx) {
                        f32x2 a = v[dx + j];
                        s[k][j] = s[k][j] + a;       // v_pk_add_f32
                        q[k][j] = q[k][j] + a * a;   // v_pk_mul + v_pk_add
                    }
                }
            }
        }
    }

    #pragma unroll
    for (int k = 0; k < 4; ++k) {
        float2 o;
        #pragma unroll
        for (int j = 0; j < 2; ++j) {
            float m1 = s[k][j].x * 0.04f;
            float e1 = q[k][j].x * 0.04f;
            float m2 = s[k][j].y * 0.04f;
            float e2 = q[k][j].y * 0.04f;
            float var1 = fmaxf(e1 - m1 * m1, 0.0f);
            float sd1 = sqrtf(var1 + 1e-9f);
            float var2 = fmaxf(e2 - m2 * m2, 0.0f);
            float sd2 = sqrtf(var2 + 1e-9f);
            float num = (2.0f * sd1) * sd2;
            float den = ((sd1 * sd1 + sd2 * sd2) + 1e-5f) + 1e-8f;
            float val = (num / den > 0.975f) ? 1.0f : 0.0f;
            (j == 0 ? o.x : o.y) = val;
        }
        size_t oidx = ((size_t)b * IMG_H + (y0 + r0 + k)) * IMG_W + (x0 + cb);
        *reinterpret_cast<float2*>(&out[oidx]) = o;
    }
}

extern "C" void kernel_launch(void* const* d_in, const int* in_sizes, int n_in,
                              void* d_out, int out_size, void* d_ws, size_t ws_size,
                              hipStream_t stream) {
    const float* img1 = (const float*)d_in[0];
    const float* img2 = (const float*)d_in[1];
    float* out = (float*)d_out;
    dim3 grid(IMG_W / TILE_W, IMG_H / TILE_H, 16);   // 8 x 16 x 16 = 2048 blocks
    texdiff_kernel<<<grid, dim3(NTHREADS), 0, stream>>>(img1, img2, out);
}